// Round 2
// 525.390 us; speedup vs baseline: 1.0495x; 1.0495x over previous
//
#include <hip/hip_runtime.h>
#include <hip/hip_bf16.h>
#include <cstdint>

// SimplifiedMambaSSM on MI355X (gfx950)
// B=8, T=4096, D_MODEL=1024, D_STATE=16. Rows M = B*T = 32768.
//
// Pipeline:
//  K1 convert : x, W_gate, [W_delta;W_B;W_C] -> bf16 workspace copies
//  K2 gemm    : G = Xb @ Wgb^T   (32768x1024x1024 bf16 MFMA, 128x128 tiles,
//               XCD-swizzled grid: each XCD owns 32 M-panels x all 8 N-tiles)
//  K3 lngate  : xg = sigmoid(LN(G + b_gate)) * x   (in-place over G, bf16)
//  K4 proj    : [delta|B|C] = xg @ Wcat^T (skinny MFMA); epilogue folds
//               softplus/exp(A_diag)/2*log2e AND the r-domain substitution:
//               writes {u = A2+B2, v = -2*A2} pairs so the scan chain is
//               fma -> exp2 -> add -> rcp (4 dependent ops). Also zeroes the
//               chunk-ready flags for K5.
//  K5 scan+out: FUSED producer-consumer kernel.
//               Blocks 0..7  : wave-specialized scan (one block per batch).
//                 Waves 1-7 stage 128-step (u,v) chunks into double-buffered
//                 LDS and flush h-history chunks to global; wave 0 lanes 0-15
//                 run the serial recurrence. After each chunk's flush is
//                 barrier-drained, tid 511 publishes flags[b] with an
//                 agent-scope release (threadfence -> buffer_wbl2 so the
//                 hs lines reach the coherence point before the flag).
//               Blocks 8..575: output GEMM  y = (C .* h) @ W_out^T + D .* x,
//                 chunk-major, spinning on flags[b] (relaxed agent loads,
//                 BOUNDED: ~0.2s fallback so a visibility bug shows up as
//                 absmax failure, never a dead container);
//                 hs read with agent-scope loads to bypass stale local L2.
//                 One-way dependency (scan never waits on out; scan blocks
//                 dispatch first) => deadlock-free by construction even
//                 without full co-residency. Grid 576 <= 768 co-resident
//                 (49.2KB LDS -> 3 blocks/CU at __launch_bounds__(512,6)).
//
// NOTE: flags lives INSIDE the Wcat padding gap (96KB used of 128KB
// reserved) so the total workspace footprint is identical to the verified
// 551us kernel (ends at 144834560). Prior round placed it past the end ->
// suspected OOB fault -> container death.
//
#define M_TOK   32768
#define LNEPS   1e-5f
#define TWO_LOG2E 2.8853900817779268f   // 2/ln(2)

typedef float  f32x4 __attribute__((ext_vector_type(4)));
typedef short  s16x8 __attribute__((ext_vector_type(8)));

__device__ __forceinline__ unsigned short f2b(float v) {
  return __builtin_bit_cast(unsigned short, __float2bfloat16(v));
}
__device__ __forceinline__ float b2f(unsigned short u) {
  return __bfloat162float(__builtin_bit_cast(__hip_bfloat16, u));
}

// async global->LDS, 16B per lane. LDS dest is wave-uniform base + lane*16.
__device__ __forceinline__ void async_cp16(const void* g, void* l) {
  using gp = const __attribute__((address_space(1))) char*;
  using lp = __attribute__((address_space(3))) char*;
  __builtin_amdgcn_global_load_lds((gp)(uint64_t)g,
                                   (lp)(uint32_t)(uint64_t)l, 16, 0, 0);
}

// ---------------------------------------------------------------- K1 convert
__global__ __launch_bounds__(256) void k_convert(
    const float* __restrict__ x, const float* __restrict__ wg,
    const float* __restrict__ wd, const float* __restrict__ wb,
    const float* __restrict__ wc,
    unsigned short* __restrict__ Xb, unsigned short* __restrict__ Wgb,
    unsigned short* __restrict__ Wcat) {
  int i = blockIdx.x * 256 + threadIdx.x;   // one float4 per thread
  const float* src;
  unsigned short* dst;
  if (i < 8388608) {                  // x: 33554432 floats
    src = x + (size_t)i * 4; dst = Xb + (size_t)i * 4;
  } else if (i < 8650752) {           // W_gate: 1048576 floats
    int j = i - 8388608;
    src = wg + (size_t)j * 4; dst = Wgb + (size_t)j * 4;
  } else {                            // Wcat = [W_delta; W_B; W_C], 49152 floats
    int j = i - 8650752;
    int e = j * 4;
    if (e < 16384)       src = wd + e;
    else if (e < 32768)  src = wb + (e - 16384);
    else                 src = wc + (e - 32768);
    dst = Wcat + e;
  }
  float4 v = *(const float4*)src;
  ushort4 o;
  o.x = f2b(v.x); o.y = f2b(v.y); o.z = f2b(v.z); o.w = f2b(v.w);
  *(ushort4*)dst = o;
}

// ------------------------------------------------------------- K2 gate GEMM
// G[m][n] = sum_k Xb[m][k] * Wgb[n][k]   (NT, both K-contiguous)
// 128x128 block tile, 4 waves in 2x2, each wave 64x64 = 4x4 MFMA 16x16x32.
__global__ __launch_bounds__(256, 2) void k_gemm_gate(
    const unsigned short* __restrict__ A,   // [32768][1024] bf16
    const unsigned short* __restrict__ Bm,  // [1024][1024] bf16 (W_gate rows)
    unsigned short* __restrict__ C) {       // [32768][1024] bf16
  __shared__ unsigned short As[128 * 32];   // 8 KB
  __shared__ unsigned short Bs[128 * 32];   // 8 KB
  const int tid  = threadIdx.x;
  const int wave = tid >> 6, lane = tid & 63;
  const int wr = wave >> 1, wc = wave & 1;
  const int lrow = lane & 15, lq = lane >> 4;
  // XCD-aware swizzle: lin 0..2047 round-robins XCDs; give each XCD a
  // contiguous chunk of 32 M-panels x all 8 N-tiles so A-panels and the
  // whole 2MB B stay L2-resident per XCD. 2048 % 8 == 0 -> bijective.
  const int lin  = blockIdx.y * gridDim.x + blockIdx.x;     // 0..2047
  const int unit = (lin & 7) * 256 + (lin >> 3);
  const int m0 = (unit >> 3) * 128;
  const int n0 = (unit & 7) * 128;
  const int crow  = tid >> 2;               // staging chunk row (rep 0)
  const int ccol  = (tid & 3) * 8;          // staging chunk col (elems)

  f32x4 acc[4][4];
#pragma unroll
  for (int i = 0; i < 4; i++)
#pragma unroll
    for (int j = 0; j < 4; j++) acc[i][j] = (f32x4){0.f, 0.f, 0.f, 0.f};

  for (int k0 = 0; k0 < 1024; k0 += 32) {
    async_cp16(A + (size_t)(m0 + crow) * 1024 + k0 + ccol,
               (void*)(As + (wave * 64) * 8));
    async_cp16(A + (size_t)(m0 + crow + 64) * 1024 + k0 + ccol,
               (void*)(As + (256 + wave * 64) * 8));
    async_cp16(Bm + (size_t)(n0 + crow) * 1024 + k0 + ccol,
               (void*)(Bs + (wave * 64) * 8));
    async_cp16(Bm + (size_t)(n0 + crow + 64) * 1024 + k0 + ccol,
               (void*)(Bs + (256 + wave * 64) * 8));
    __syncthreads();   // drains vmcnt (global_load_lds) before LDS reads

    s16x8 af[4], bfr[4];
#pragma unroll
    for (int i = 0; i < 4; i++)
      af[i] = *(const s16x8*)(As + (wr * 64 + i * 16 + lrow) * 32 + lq * 8);
#pragma unroll
    for (int j = 0; j < 4; j++)
      bfr[j] = *(const s16x8*)(Bs + (wc * 64 + j * 16 + lrow) * 32 + lq * 8);
#pragma unroll
    for (int i = 0; i < 4; i++)
#pragma unroll
      for (int j = 0; j < 4; j++)
        acc[i][j] = __builtin_amdgcn_mfma_f32_16x16x32_bf16(
            af[i], bfr[j], acc[i][j], 0, 0, 0);
    __syncthreads();
  }

  // C/D layout: col = lane&15, row = (lane>>4)*4 + reg
#pragma unroll
  for (int i = 0; i < 4; i++)
#pragma unroll
    for (int j = 0; j < 4; j++)
#pragma unroll
      for (int r = 0; r < 4; r++) {
        int row = m0 + wr * 64 + i * 16 + lq * 4 + r;
        int col = n0 + wc * 64 + j * 16 + lrow;
        C[(size_t)row * 1024 + col] = f2b(acc[i][j][r]);
      }
}

// -------------------------------------------------------------- K3 LN+gate
__global__ __launch_bounds__(256) void k_lngate(
    const unsigned short* Gin, const float* __restrict__ x,
    const float* __restrict__ bg, const float* __restrict__ lnw,
    const float* __restrict__ lnb, unsigned short* XG) {
  __shared__ float red[8];
  const int t = threadIdx.x;
  const size_t r = blockIdx.x;
  const int e = t * 4;

  ushort4 g4 = *(const ushort4*)(Gin + r * 1024 + e);
  float4 bg4 = *(const float4*)(bg + e);
  float v0 = b2f(g4.x) + bg4.x;
  float v1 = b2f(g4.y) + bg4.y;
  float v2 = b2f(g4.z) + bg4.z;
  float v3 = b2f(g4.w) + bg4.w;

  float s  = v0 + v1 + v2 + v3;
  float ss = v0 * v0 + v1 * v1 + v2 * v2 + v3 * v3;
#pragma unroll
  for (int off = 32; off >= 1; off >>= 1) {
    s  += __shfl_xor(s, off, 64);
    ss += __shfl_xor(ss, off, 64);
  }
  if ((t & 63) == 0) { red[t >> 6] = s; red[4 + (t >> 6)] = ss; }
  __syncthreads();
  float tot = red[0] + red[1] + red[2] + red[3];
  float tss = red[4] + red[5] + red[6] + red[7];
  float mu  = tot * (1.0f / 1024.0f);
  float var = tss * (1.0f / 1024.0f) - mu * mu;
  float rs  = rsqrtf(var + LNEPS);

  float4 xv = *(const float4*)(x + r * 1024 + e);
  float4 w4 = *(const float4*)(lnw + e);
  float4 b4 = *(const float4*)(lnb + e);
  float u0 = (v0 - mu) * rs * w4.x + b4.x;
  float u1 = (v1 - mu) * rs * w4.y + b4.y;
  float u2 = (v2 - mu) * rs * w4.z + b4.z;
  float u3 = (v3 - mu) * rs * w4.w + b4.w;
  float g0 = 1.0f / (1.0f + __expf(-u0));
  float g1 = 1.0f / (1.0f + __expf(-u1));
  float g2 = 1.0f / (1.0f + __expf(-u2));
  float g3 = 1.0f / (1.0f + __expf(-u3));
  ushort4 o;
  o.x = f2b(g0 * xv.x); o.y = f2b(g1 * xv.y);
  o.z = f2b(g2 * xv.z); o.w = f2b(g3 * xv.w);
  *(ushort4*)(XG + r * 1024 + e) = o;
}

// ------------------------------------------------------------ K4 projection
// Epilogue writes UV[row*32 + s*2] = {u = A2+B2, v = -2*A2} where
// A2 = exp(softplus(delta)*A_diag)*2log2e, B2 = B*2log2e. Ct written flat.
// Also zeroes the 8 chunk-ready flags consumed by K5 (this kernel precedes
// K5 in stream order every graph replay; its end-of-dispatch writeback
// makes the zeros visible to K5's agent-scope polls).
__global__ __launch_bounds__(256) void k_proj(
    const unsigned short* __restrict__ XG, const unsigned short* __restrict__ Wcat,
    const float* __restrict__ A_diag,
    float* __restrict__ UV, float* __restrict__ Ct, int* __restrict__ flags) {
  __shared__ unsigned short As[64 * 32];   // 4 KB
  __shared__ unsigned short Bs[48 * 32];   // 3 KB
  const int tid  = threadIdx.x;
  const int wave = tid >> 6, lane = tid & 63;
  const int lrow = lane & 15, lq = lane >> 4;
  const int r0 = blockIdx.x * 64;
  const int crow = tid >> 2, ccol = (tid & 3) * 8;

  if (blockIdx.x == 0 && tid < 8) flags[tid] = 0;

  f32x4 acc[3];
#pragma unroll
  for (int j = 0; j < 3; j++) acc[j] = (f32x4){0.f, 0.f, 0.f, 0.f};

  for (int k0 = 0; k0 < 1024; k0 += 32) {
    uint4 av = *(const uint4*)(XG + (size_t)(r0 + crow) * 1024 + k0 + ccol);
    uint4 bv;
    if (tid < 192) bv = *(const uint4*)(Wcat + (size_t)crow * 1024 + k0 + ccol);
    __syncthreads();                       // prev iter done reading LDS
    *(uint4*)(As + crow * 32 + ccol) = av;
    if (tid < 192) *(uint4*)(Bs + crow * 32 + ccol) = bv;
    __syncthreads();
    s16x8 af = *(const s16x8*)(As + (wave * 16 + lrow) * 32 + lq * 8);
#pragma unroll
    for (int j = 0; j < 3; j++) {
      s16x8 bf8 = *(const s16x8*)(Bs + (j * 16 + lrow) * 32 + lq * 8);
      acc[j] = __builtin_amdgcn_mfma_f32_16x16x32_bf16(af, bf8, acc[j], 0, 0, 0);
    }
  }

  float ad = A_diag[lrow];
#pragma unroll
  for (int r = 0; r < 4; r++) {
    int row = r0 + wave * 16 + lq * 4 + r;
    float z  = acc[0][r];
    float sp = fmaxf(z, 0.0f) + log1pf(__expf(-fabsf(z)));  // softplus
    float A2 = __expf(sp * ad) * TWO_LOG2E;                  // A_bar scaled
    float B2 = acc[1][r] * TWO_LOG2E;
    float2 o;
    o.x = A2 + B2;          // u
    o.y = -2.0f * A2;       // v
    *(float2*)(UV + (size_t)row * 32 + lrow * 2) = o;
    Ct[(size_t)row * 16 + lrow] = acc[2][r];
  }
}

// --------------------------------------------------------- K5 scan + output
// Blocks 0..7: wave-specialized scan (one per batch). Blocks 8..: output
// GEMM consuming hs chunk-by-chunk via flags. See header comment.
#define TC 128                // steps per chunk
#define NCH (4096 / TC)       // 32 chunks
#define NOUT 568              // output blocks; grid = 8 + NOUT = 576 <= 768 cap

__device__ __forceinline__ void load16(float2 (&P)[16], const float* uvb,
                                       int j, int lane) {
#pragma unroll
  for (int i = 0; i < 16; ++i)
    P[i] = *(const float2*)(uvb + ((j * 16 + i) * 16 + lane) * 2);
}
__device__ __forceinline__ void fast16(float2 (&P)[16], float& r, float& h,
                                       float* hhb, int j, int lane) {
#pragma unroll
  for (int i = 0; i < 16; ++i) {
    float w = fmaf(P[i].y, r, P[i].x);
    float e = __builtin_amdgcn_exp2f(w);
    r = __builtin_amdgcn_rcpf(e + 1.0f);
    h = fmaf(-2.0f, r, 1.0f);
    hhb[(j * 16 + i) * 16 + lane] = h;
  }
}
__device__ __forceinline__ void slow16(float2 (&P)[16], float& h,
                                       const float* mb, float* hhb,
                                       int j, int lane) {
#pragma unroll
  for (int i = 0; i < 16; ++i) {
    float v  = P[i].y, u = P[i].x;
    float A2 = -0.5f * v;
    float B2 = fmaf(0.5f, v, u);
    float w  = fmaf(A2, h, B2);
    float e  = __builtin_amdgcn_exp2f(w);
    float rr = __builtin_amdgcn_rcpf(e + 1.0f);
    float th = fmaf(-2.0f, rr, 1.0f);
    float m  = mb[j * 16 + i];
    h = fmaf(m, th - h, h);
    hhb[(j * 16 + i) * 16 + lane] = h;
  }
}

__global__ __launch_bounds__(512, 6) void k_scan_out(
    const float* __restrict__ UV, const float* __restrict__ mask,
    const float* __restrict__ h0, float* __restrict__ hs,
    float* __restrict__ hfin,
    const float* __restrict__ Ct, const float* __restrict__ x,
    const float* __restrict__ Wout, const float* __restrict__ Dd,
    float* __restrict__ y, int* __restrict__ flags) {
  __shared__ float uvL[2][TC * 32];    // 2 x 16 KB
  __shared__ float hhL[2][TC * 16];    // 2 x 8 KB
  __shared__ float mskL[2][TC];        // 2 x 512 B

  const int tid = threadIdx.x;

  if (blockIdx.x >= 8) {
    // ============================ OUTPUT ROLE ============================
    // y[r][d] = D[d]*x[r][d] + sum_s W_out[d][s] * (Ct[r][s]*hs[r][s])
    // 8 waves cover the 1024 cols (wave w: cols [w*128, w*128+128), 2/lane).
    // Chunk-major row order matches scan production order.
    const int o    = blockIdx.x - 8;          // 0..NOUT-1
    const int wv   = tid >> 6;
    const int lane = tid & 63;
    const int d0   = wv * 128 + lane * 2;

    float wa[16], wb[16];
#pragma unroll
    for (int q = 0; q < 4; q++) {
      *(float4*)&wa[q * 4] = *(const float4*)(Wout + (size_t)d0 * 16 + q * 4);
      *(float4*)&wb[q * 4] = *(const float4*)(Wout + (size_t)(d0 + 1) * 16 + q * 4);
    }
    float2 D2 = *(const float2*)(Dd + d0);

    for (int c = 0; c < NCH; ++c) {
      for (int idx = o; idx < 1024; idx += NOUT) {
        int b = idx >> 7, j = idx & 127;
        size_t r = (size_t)b * 4096 + (size_t)c * TC + j;
        // wait until chunk c of batch b is published. BOUNDED: ~0.2s cap
        // (2^18 sleeps x ~2k cyc) converts any visibility pathology into
        // a wrong-answer instead of a hung container. Never hit normally.
        int spins = 0;
        for (;;) {
          int f = 0;
          if (lane == 0)
            f = __hip_atomic_load(&flags[b], __ATOMIC_RELAXED,
                                  __HIP_MEMORY_SCOPE_AGENT);
          f = __shfl(f, 0);
          if (f > c || spins > (1 << 18)) break;
          ++spins;
          __builtin_amdgcn_s_sleep(32);
        }
        float cv = Ct[r * 16 + (lane & 15)];
        // agent-scope load: bypass local L2 (may hold stale lines from the
        // previous graph replay); writer side wbl2'd these to the
        // coherence point before publishing the flag.
        float hv = __hip_atomic_load(&hs[r * 16 + (lane & 15)],
                                     __ATOMIC_RELAXED, __HIP_MEMORY_SCOPE_AGENT);
        float sv = cv * hv;
        float2 x2 = *(const float2*)(x + r * 1024 + d0);
        float accx = D2.x * x2.x, accy = D2.y * x2.y;
#pragma unroll
        for (int s = 0; s < 16; s++) {
          float svs = __shfl(sv, s);
          accx = fmaf(wa[s], svs, accx);
          accy = fmaf(wb[s], svs, accy);
        }
        float2 o2; o2.x = accx; o2.y = accy;
        *(float2*)(y + r * 1024 + d0) = o2;
      }
    }
    return;
  }

  // ============================== SCAN ROLE ==============================
  const int b   = blockIdx.x;
  const float* pm = mask + (size_t)b * 4096;
  const size_t uvbase = (size_t)b * 4096 * 32;   // floats
  const size_t hsbase = (size_t)b * 4096 * 16;   // floats

  float h = 0.f, r = 0.f;
  if (tid < 16) {
    h = h0[b * 16 + tid];
    r = 0.5f - 0.5f * h;        // invariant r = (1-h)/2
  }

  // ---- priming: load chunk 0 (UV + mask)
  if (tid >= 64) {
    int pt = tid - 64;                          // 0..447
    const uint4* src = (const uint4*)(UV + uvbase);
    for (int i = pt; i < TC * 8; i += 448) ((uint4*)uvL[0])[i] = src[i];
    if (tid < 128) {
      int l = tid - 64;
      mskL[0][l]      = pm[l];
      mskL[0][l + 64] = pm[l + 64];
    }
  }
  __syncthreads();

  for (int c = 0; c < NCH; ++c) {
    // publish chunks 0..c-2 (flushed during iter c-1, drained by its
    // barrier). threadfence = agent release: buffer_wbl2 pushes the other
    // threads' already-completed hs stores to the coherence point.
    if (c >= 2 && tid == 511) {
      __threadfence();
      __hip_atomic_store(&flags[b], c - 1, __ATOMIC_RELEASE,
                         __HIP_MEMORY_SCOPE_AGENT);
    }
    const int p = c & 1;
    if (tid < 64) {
      // ---------------- consumer wave
      const int lane = tid;
      float mv0 = mskL[p][2 * lane], mv1 = mskL[p][2 * lane + 1];
      bool on = (mv0 == 1.0f) && (mv1 == 1.0f);
      bool allones = (__ballot(on) == 0xFFFFFFFFFFFFFFFFull);
      if (lane < 16) {
        const float* uvb = uvL[p];
        float* hhb = hhL[p];
        float2 Pa[16], Pb[16];
        load16(Pa, uvb, 0, lane);
        if (allones) {
#pragma unroll
          for (int j = 0; j < 8; j += 2) {
            load16(Pb, uvb, j + 1, lane);
            fast16(Pa, r, h, hhb, j, lane);
            if (j + 2 < 8) load16(Pa, uvb, j + 2, lane);
            fast16(Pb, r, h, hhb, j + 1, lane);
          }
          // h already = 1 - 2r
        } else {
#pragma unroll
          for (int j = 0; j < 8; j += 2) {
            load16(Pb, uvb, j + 1, lane);
            slow16(Pa, h, mskL[p], hhb, j, lane);
            if (j + 2 < 8) load16(Pa, uvb, j + 2, lane);
            slow16(Pb, h, mskL[p], hhb, j + 1, lane);
          }
          r = 0.5f - 0.5f * h;
        }
      }
    } else {
      // ---------------- producer waves 1..7
      int pt = tid - 64;                        // 0..447
      if (c + 1 < NCH) {
        const uint4* src =
            (const uint4*)(UV + uvbase + (size_t)(c + 1) * TC * 32);
        uint4* dst = (uint4*)uvL[(c + 1) & 1];
        for (int i = pt; i < TC * 8; i += 448) dst[i] = src[i];
        if (tid < 128) {
          int l = tid - 64;
          mskL[(c + 1) & 1][l]      = pm[(c + 1) * TC + l];
          mskL[(c + 1) & 1][l + 64] = pm[(c + 1) * TC + l + 64];
        }
      }
      if (c > 0) {
        const uint4* s2 = (const uint4*)hhL[(c - 1) & 1];
        uint4* d2 = (uint4*)(hs + hsbase + (size_t)(c - 1) * TC * 16);
        for (int i = pt; i < TC * 4; i += 448) d2[i] = s2[i];
      }
    }
    __syncthreads();
  }

  // ---- epilogue: store last chunk's h-history (parity (NCH-1)&1 = 1)
  {
    const uint4* s2 = (const uint4*)hhL[(NCH - 1) & 1];
    uint4* d2 = (uint4*)(hs + hsbase + (size_t)(NCH - 1) * TC * 16);
    if (tid < TC * 4) d2[tid] = s2[tid];
  }
  __syncthreads();                              // drain epilogue + ch30 flush
  if (tid == 511) {
    __threadfence();
    __hip_atomic_store(&flags[b], NCH, __ATOMIC_RELEASE,
                       __HIP_MEMORY_SCOPE_AGENT);
  }
  if (tid < 16) hfin[b * 16 + tid] = h;
}

// ---------------------------------------------------------------- launcher
extern "C" void kernel_launch(void* const* d_in, const int* in_sizes, int n_in,
                              void* d_out, int out_size, void* d_ws, size_t ws_size,
                              hipStream_t stream) {
  const float* x       = (const float*)d_in[0];
  const float* h0      = (const float*)d_in[1];
  const float* mask    = (const float*)d_in[2];
  const float* A_diag  = (const float*)d_in[3];
  const float* W_delta = (const float*)d_in[4];
  const float* W_B     = (const float*)d_in[5];
  const float* W_C     = (const float*)d_in[6];
  const float* W_out   = (const float*)d_in[7];
  const float* Dd      = (const float*)d_in[8];
  const float* W_gate  = (const float*)d_in[9];
  const float* b_gate  = (const float*)d_in[10];
  const float* ln_w    = (const float*)d_in[11];
  const float* ln_b    = (const float*)d_in[12];

  char* ws = (char*)d_ws;
  unsigned short* Xb   = (unsigned short*)(ws);               // 64 MB
  unsigned short* Gb   = (unsigned short*)(ws + 67108864);    // 64 MB (G, then xg in-place)
  unsigned short* Wgb  = (unsigned short*)(ws + 134217728);   // 2 MB
  unsigned short* Wcat = (unsigned short*)(ws + 136314880);   // 96 KB used of 128 KB slot
  int* flags = (int*)(ws + 136413184);                        // 32 B, inside Wcat pad gap
  float* UVb = (float*)(ws + 136445952);                      // 4 MB interleaved {u,v}
  float* Ctb = (float*)(ws + 140640256);                      // 2 MB
  float* hsb = (float*)(ws + 142737408);                      // 2 MB  (end 144834560, same as verified kernel)

  float* y    = (float*)d_out;
  float* hfin = y + 33554432;

  hipLaunchKernelGGL(k_convert, dim3(33840), dim3(256), 0, stream,
                     x, W_gate, W_delta, W_B, W_C, Xb, Wgb, Wcat);
  hipLaunchKernelGGL(k_gemm_gate, dim3(256, 8), dim3(256), 0, stream, Xb, Wgb, Gb);
  hipLaunchKernelGGL(k_lngate, dim3(32768), dim3(256), 0, stream,
                     Gb, x, b_gate, ln_w, ln_b, Gb);
  hipLaunchKernelGGL(k_proj, dim3(512), dim3(256), 0, stream,
                     Gb, Wcat, A_diag, UVb, Ctb, flags);
  hipLaunchKernelGGL(k_scan_out, dim3(8 + NOUT), dim3(512), 0, stream,
                     UVb, mask, h0, hsb, hfin, Ctb, x, W_out, Dd, y, flags);
}

// Round 3
// 506.809 us; speedup vs baseline: 1.0880x; 1.0367x over previous
//
#include <hip/hip_runtime.h>
#include <hip/hip_bf16.h>
#include <cstdint>

// SimplifiedMambaSSM on MI355X (gfx950)
// B=8, T=4096, D_MODEL=1024, D_STATE=16. Rows M = B*T = 32768.
//
// Pipeline:
//  K1 convert : x, W_gate, [W_delta;W_B;W_C] -> bf16 workspace copies
//  K2 gemm    : G = Xb @ Wgb^T   (32768x1024x1024 bf16 MFMA, 128x128 tiles,
//               XCD-swizzled grid: each XCD owns 32 M-panels x all 8 N-tiles)
//  K3 lngate  : xg = sigmoid(LN(G + b_gate)) * x   (in-place over G, bf16)
//  K4 proj    : [delta|B|C] = xg @ Wcat^T (skinny MFMA); epilogue folds
//               softplus/exp(A_diag)/2*log2e AND the r-domain substitution:
//               writes {u = A2+B2, v = -2*A2} pairs so the scan chain is
//               fma -> exp2 -> add -> rcp (4 dependent ops). Also zeroes the
//               chunk-ready flags for K5.
//  K5 scan+out: FUSED producer-consumer kernel.
//               Blocks 0..7  : wave-specialized scan (one block per batch).
//                 Waves 1-7 stage 128-step (u,v) chunks into double-buffered
//                 LDS and flush h-history chunks to global with AGENT-SCOPE
//                 WRITE-THROUGH stores (sc0 sc1 -> coherence point). The
//                 pre-barrier vmcnt(0) drain that __syncthreads already
//                 emits makes chunk c-2 globally visible at the iteration-c
//                 boundary, so the flag publish is a bare RELAXED agent
//                 store -- NO __threadfence/buffer_wbl2. (R2 lesson: the
//                 per-chunk wbl2 flushed ~0.5MB of co-resident output
//                 blocks' dirty y-lines and stalled wave 7 ~1.2us/chunk =
//                 the whole 40us gap vs the standalone 107us scan.)
//               Blocks 8..575: output GEMM  y = (C .* h) @ W_out^T + D .* x,
//                 chunk-major, spinning on flags[b] (relaxed agent loads,
//                 BOUNDED: ~0.2s fallback so a visibility bug shows up as
//                 absmax failure, never a dead container);
//                 hs read with agent-scope loads to bypass stale local L2.
//                 One-way dependency (scan never waits on out; scan blocks
//                 dispatch first) => deadlock-free by construction even
//                 without full co-residency. Grid 576 <= 768 co-resident
//                 (49.2KB LDS -> 3 blocks/CU at __launch_bounds__(512,6)).
//
#define M_TOK   32768
#define LNEPS   1e-5f
#define TWO_LOG2E 2.8853900817779268f   // 2/ln(2)

typedef float  f32x4 __attribute__((ext_vector_type(4)));
typedef short  s16x8 __attribute__((ext_vector_type(8)));

__device__ __forceinline__ unsigned short f2b(float v) {
  return __builtin_bit_cast(unsigned short, __float2bfloat16(v));
}
__device__ __forceinline__ float b2f(unsigned short u) {
  return __bfloat162float(__builtin_bit_cast(__hip_bfloat16, u));
}

// async global->LDS, 16B per lane. LDS dest is wave-uniform base + lane*16.
__device__ __forceinline__ void async_cp16(const void* g, void* l) {
  using gp = const __attribute__((address_space(1))) char*;
  using lp = __attribute__((address_space(3))) char*;
  __builtin_amdgcn_global_load_lds((gp)(uint64_t)g,
                                   (lp)(uint32_t)(uint64_t)l, 16, 0, 0);
}

// ---------------------------------------------------------------- K1 convert
__global__ __launch_bounds__(256) void k_convert(
    const float* __restrict__ x, const float* __restrict__ wg,
    const float* __restrict__ wd, const float* __restrict__ wb,
    const float* __restrict__ wc,
    unsigned short* __restrict__ Xb, unsigned short* __restrict__ Wgb,
    unsigned short* __restrict__ Wcat) {
  int i = blockIdx.x * 256 + threadIdx.x;   // one float4 per thread
  const float* src;
  unsigned short* dst;
  if (i < 8388608) {                  // x: 33554432 floats
    src = x + (size_t)i * 4; dst = Xb + (size_t)i * 4;
  } else if (i < 8650752) {           // W_gate: 1048576 floats
    int j = i - 8388608;
    src = wg + (size_t)j * 4; dst = Wgb + (size_t)j * 4;
  } else {                            // Wcat = [W_delta; W_B; W_C], 49152 floats
    int j = i - 8650752;
    int e = j * 4;
    if (e < 16384)       src = wd + e;
    else if (e < 32768)  src = wb + (e - 16384);
    else                 src = wc + (e - 32768);
    dst = Wcat + e;
  }
  float4 v = *(const float4*)src;
  ushort4 o;
  o.x = f2b(v.x); o.y = f2b(v.y); o.z = f2b(v.z); o.w = f2b(v.w);
  *(ushort4*)dst = o;
}

// ------------------------------------------------------------- K2 gate GEMM
// G[m][n] = sum_k Xb[m][k] * Wgb[n][k]   (NT, both K-contiguous)
// 128x128 block tile, 4 waves in 2x2, each wave 64x64 = 4x4 MFMA 16x16x32.
__global__ __launch_bounds__(256, 2) void k_gemm_gate(
    const unsigned short* __restrict__ A,   // [32768][1024] bf16
    const unsigned short* __restrict__ Bm,  // [1024][1024] bf16 (W_gate rows)
    unsigned short* __restrict__ C) {       // [32768][1024] bf16
  __shared__ unsigned short As[128 * 32];   // 8 KB
  __shared__ unsigned short Bs[128 * 32];   // 8 KB
  const int tid  = threadIdx.x;
  const int wave = tid >> 6, lane = tid & 63;
  const int wr = wave >> 1, wc = wave & 1;
  const int lrow = lane & 15, lq = lane >> 4;
  // XCD-aware swizzle: lin 0..2047 round-robins XCDs; give each XCD a
  // contiguous chunk of 32 M-panels x all 8 N-tiles so A-panels and the
  // whole 2MB B stay L2-resident per XCD. 2048 % 8 == 0 -> bijective.
  const int lin  = blockIdx.y * gridDim.x + blockIdx.x;     // 0..2047
  const int unit = (lin & 7) * 256 + (lin >> 3);
  const int m0 = (unit >> 3) * 128;
  const int n0 = (unit & 7) * 128;
  const int crow  = tid >> 2;               // staging chunk row (rep 0)
  const int ccol  = (tid & 3) * 8;          // staging chunk col (elems)

  f32x4 acc[4][4];
#pragma unroll
  for (int i = 0; i < 4; i++)
#pragma unroll
    for (int j = 0; j < 4; j++) acc[i][j] = (f32x4){0.f, 0.f, 0.f, 0.f};

  for (int k0 = 0; k0 < 1024; k0 += 32) {
    async_cp16(A + (size_t)(m0 + crow) * 1024 + k0 + ccol,
               (void*)(As + (wave * 64) * 8));
    async_cp16(A + (size_t)(m0 + crow + 64) * 1024 + k0 + ccol,
               (void*)(As + (256 + wave * 64) * 8));
    async_cp16(Bm + (size_t)(n0 + crow) * 1024 + k0 + ccol,
               (void*)(Bs + (wave * 64) * 8));
    async_cp16(Bm + (size_t)(n0 + crow + 64) * 1024 + k0 + ccol,
               (void*)(Bs + (256 + wave * 64) * 8));
    __syncthreads();   // drains vmcnt (global_load_lds) before LDS reads

    s16x8 af[4], bfr[4];
#pragma unroll
    for (int i = 0; i < 4; i++)
      af[i] = *(const s16x8*)(As + (wr * 64 + i * 16 + lrow) * 32 + lq * 8);
#pragma unroll
    for (int j = 0; j < 4; j++)
      bfr[j] = *(const s16x8*)(Bs + (wc * 64 + j * 16 + lrow) * 32 + lq * 8);
#pragma unroll
    for (int i = 0; i < 4; i++)
#pragma unroll
      for (int j = 0; j < 4; j++)
        acc[i][j] = __builtin_amdgcn_mfma_f32_16x16x32_bf16(
            af[i], bfr[j], acc[i][j], 0, 0, 0);
    __syncthreads();
  }

  // C/D layout: col = lane&15, row = (lane>>4)*4 + reg
#pragma unroll
  for (int i = 0; i < 4; i++)
#pragma unroll
    for (int j = 0; j < 4; j++)
#pragma unroll
      for (int r = 0; r < 4; r++) {
        int row = m0 + wr * 64 + i * 16 + lq * 4 + r;
        int col = n0 + wc * 64 + j * 16 + lrow;
        C[(size_t)row * 1024 + col] = f2b(acc[i][j][r]);
      }
}

// -------------------------------------------------------------- K3 LN+gate
__global__ __launch_bounds__(256) void k_lngate(
    const unsigned short* Gin, const float* __restrict__ x,
    const float* __restrict__ bg, const float* __restrict__ lnw,
    const float* __restrict__ lnb, unsigned short* XG) {
  __shared__ float red[8];
  const int t = threadIdx.x;
  const size_t r = blockIdx.x;
  const int e = t * 4;

  ushort4 g4 = *(const ushort4*)(Gin + r * 1024 + e);
  float4 bg4 = *(const float4*)(bg + e);
  float v0 = b2f(g4.x) + bg4.x;
  float v1 = b2f(g4.y) + bg4.y;
  float v2 = b2f(g4.z) + bg4.z;
  float v3 = b2f(g4.w) + bg4.w;

  float s  = v0 + v1 + v2 + v3;
  float ss = v0 * v0 + v1 * v1 + v2 * v2 + v3 * v3;
#pragma unroll
  for (int off = 32; off >= 1; off >>= 1) {
    s  += __shfl_xor(s, off, 64);
    ss += __shfl_xor(ss, off, 64);
  }
  if ((t & 63) == 0) { red[t >> 6] = s; red[4 + (t >> 6)] = ss; }
  __syncthreads();
  float tot = red[0] + red[1] + red[2] + red[3];
  float tss = red[4] + red[5] + red[6] + red[7];
  float mu  = tot * (1.0f / 1024.0f);
  float var = tss * (1.0f / 1024.0f) - mu * mu;
  float rs  = rsqrtf(var + LNEPS);

  float4 xv = *(const float4*)(x + r * 1024 + e);
  float4 w4 = *(const float4*)(lnw + e);
  float4 b4 = *(const float4*)(lnb + e);
  float u0 = (v0 - mu) * rs * w4.x + b4.x;
  float u1 = (v1 - mu) * rs * w4.y + b4.y;
  float u2 = (v2 - mu) * rs * w4.z + b4.z;
  float u3 = (v3 - mu) * rs * w4.w + b4.w;
  float g0 = 1.0f / (1.0f + __expf(-u0));
  float g1 = 1.0f / (1.0f + __expf(-u1));
  float g2 = 1.0f / (1.0f + __expf(-u2));
  float g3 = 1.0f / (1.0f + __expf(-u3));
  ushort4 o;
  o.x = f2b(g0 * xv.x); o.y = f2b(g1 * xv.y);
  o.z = f2b(g2 * xv.z); o.w = f2b(g3 * xv.w);
  *(ushort4*)(XG + r * 1024 + e) = o;
}

// ------------------------------------------------------------ K4 projection
// Epilogue writes UV[row*32 + s*2] = {u = A2+B2, v = -2*A2} where
// A2 = exp(softplus(delta)*A_diag)*2log2e, B2 = B*2log2e. Ct written flat.
// Also zeroes the 8 chunk-ready flags consumed by K5 (this kernel precedes
// K5 in stream order every graph replay; its end-of-dispatch writeback
// makes the zeros visible to K5's agent-scope polls).
__global__ __launch_bounds__(256) void k_proj(
    const unsigned short* __restrict__ XG, const unsigned short* __restrict__ Wcat,
    const float* __restrict__ A_diag,
    float* __restrict__ UV, float* __restrict__ Ct, int* __restrict__ flags) {
  __shared__ unsigned short As[64 * 32];   // 4 KB
  __shared__ unsigned short Bs[48 * 32];   // 3 KB
  const int tid  = threadIdx.x;
  const int wave = tid >> 6, lane = tid & 63;
  const int lrow = lane & 15, lq = lane >> 4;
  const int r0 = blockIdx.x * 64;
  const int crow = tid >> 2, ccol = (tid & 3) * 8;

  if (blockIdx.x == 0 && tid < 8)
    __hip_atomic_store(&flags[tid], 0, __ATOMIC_RELAXED,
                       __HIP_MEMORY_SCOPE_AGENT);   // write-through zeroing

  f32x4 acc[3];
#pragma unroll
  for (int j = 0; j < 3; j++) acc[j] = (f32x4){0.f, 0.f, 0.f, 0.f};

  for (int k0 = 0; k0 < 1024; k0 += 32) {
    uint4 av = *(const uint4*)(XG + (size_t)(r0 + crow) * 1024 + k0 + ccol);
    uint4 bv;
    if (tid < 192) bv = *(const uint4*)(Wcat + (size_t)crow * 1024 + k0 + ccol);
    __syncthreads();                       // prev iter done reading LDS
    *(uint4*)(As + crow * 32 + ccol) = av;
    if (tid < 192) *(uint4*)(Bs + crow * 32 + ccol) = bv;
    __syncthreads();
    s16x8 af = *(const s16x8*)(As + (wave * 16 + lrow) * 32 + lq * 8);
#pragma unroll
    for (int j = 0; j < 3; j++) {
      s16x8 bf8 = *(const s16x8*)(Bs + (j * 16 + lrow) * 32 + lq * 8);
      acc[j] = __builtin_amdgcn_mfma_f32_16x16x32_bf16(af, bf8, acc[j], 0, 0, 0);
    }
  }

  float ad = A_diag[lrow];
#pragma unroll
  for (int r = 0; r < 4; r++) {
    int row = r0 + wave * 16 + lq * 4 + r;
    float z  = acc[0][r];
    float sp = fmaxf(z, 0.0f) + log1pf(__expf(-fabsf(z)));  // softplus
    float A2 = __expf(sp * ad) * TWO_LOG2E;                  // A_bar scaled
    float B2 = acc[1][r] * TWO_LOG2E;
    float2 o;
    o.x = A2 + B2;          // u
    o.y = -2.0f * A2;       // v
    *(float2*)(UV + (size_t)row * 32 + lrow * 2) = o;
    Ct[(size_t)row * 16 + lrow] = acc[2][r];
  }
}

// --------------------------------------------------------- K5 scan + output
// Blocks 0..7: wave-specialized scan (one per batch). Blocks 8..: output
// GEMM consuming hs chunk-by-chunk via flags. See header comment.
#define TC 128                // steps per chunk
#define NCH (4096 / TC)       // 32 chunks
#define NOUT 568              // output blocks; grid = 8 + NOUT = 576 <= 768 cap

__device__ __forceinline__ void load16(float2 (&P)[16], const float* uvb,
                                       int j, int lane) {
#pragma unroll
  for (int i = 0; i < 16; ++i)
    P[i] = *(const float2*)(uvb + ((j * 16 + i) * 16 + lane) * 2);
}
__device__ __forceinline__ void fast16(float2 (&P)[16], float& r, float& h,
                                       float* hhb, int j, int lane) {
#pragma unroll
  for (int i = 0; i < 16; ++i) {
    float w = fmaf(P[i].y, r, P[i].x);
    float e = __builtin_amdgcn_exp2f(w);
    r = __builtin_amdgcn_rcpf(e + 1.0f);
    h = fmaf(-2.0f, r, 1.0f);
    hhb[(j * 16 + i) * 16 + lane] = h;
  }
}
__device__ __forceinline__ void slow16(float2 (&P)[16], float& h,
                                       const float* mb, float* hhb,
                                       int j, int lane) {
#pragma unroll
  for (int i = 0; i < 16; ++i) {
    float v  = P[i].y, u = P[i].x;
    float A2 = -0.5f * v;
    float B2 = fmaf(0.5f, v, u);
    float w  = fmaf(A2, h, B2);
    float e  = __builtin_amdgcn_exp2f(w);
    float rr = __builtin_amdgcn_rcpf(e + 1.0f);
    float th = fmaf(-2.0f, rr, 1.0f);
    float m  = mb[j * 16 + i];
    h = fmaf(m, th - h, h);
    hhb[(j * 16 + i) * 16 + lane] = h;
  }
}

__global__ __launch_bounds__(512, 6) void k_scan_out(
    const float* __restrict__ UV, const float* __restrict__ mask,
    const float* __restrict__ h0, float* __restrict__ hs,
    float* __restrict__ hfin,
    const float* __restrict__ Ct, const float* __restrict__ x,
    const float* __restrict__ Wout, const float* __restrict__ Dd,
    float* __restrict__ y, int* __restrict__ flags) {
  __shared__ float uvL[2][TC * 32];    // 2 x 16 KB
  __shared__ float hhL[2][TC * 16];    // 2 x 8 KB
  __shared__ float mskL[2][TC];        // 2 x 512 B

  const int tid = threadIdx.x;

  if (blockIdx.x >= 8) {
    // ============================ OUTPUT ROLE ============================
    // y[r][d] = D[d]*x[r][d] + sum_s W_out[d][s] * (Ct[r][s]*hs[r][s])
    // 8 waves cover the 1024 cols (wave w: cols [w*128, w*128+128), 2/lane).
    // Chunk-major row order matches scan production order.
    const int o    = blockIdx.x - 8;          // 0..NOUT-1
    const int wv   = tid >> 6;
    const int lane = tid & 63;
    const int d0   = wv * 128 + lane * 2;

    float wa[16], wb[16];
#pragma unroll
    for (int q = 0; q < 4; q++) {
      *(float4*)&wa[q * 4] = *(const float4*)(Wout + (size_t)d0 * 16 + q * 4);
      *(float4*)&wb[q * 4] = *(const float4*)(Wout + (size_t)(d0 + 1) * 16 + q * 4);
    }
    float2 D2 = *(const float2*)(Dd + d0);

    for (int c = 0; c < NCH; ++c) {
      for (int idx = o; idx < 1024; idx += NOUT) {
        int b = idx >> 7, j = idx & 127;
        size_t r = (size_t)b * 4096 + (size_t)c * TC + j;
        // wait until chunk c of batch b is published. BOUNDED: ~0.2s cap
        // (2^18 sleeps x ~2k cyc) converts any visibility pathology into
        // a wrong-answer instead of a hung container. Never hit normally.
        int spins = 0;
        for (;;) {
          int f = 0;
          if (lane == 0)
            f = __hip_atomic_load(&flags[b], __ATOMIC_RELAXED,
                                  __HIP_MEMORY_SCOPE_AGENT);
          f = __shfl(f, 0);
          if (f > c || spins > (1 << 18)) break;
          ++spins;
          __builtin_amdgcn_s_sleep(32);
        }
        float cv = Ct[r * 16 + (lane & 15)];
        // agent-scope load: bypass local L2 (may hold stale lines from the
        // previous graph replay); writer side stored these write-through
        // (sc0 sc1) and drained vmcnt before publishing the flag.
        float hv = __hip_atomic_load(&hs[r * 16 + (lane & 15)],
                                     __ATOMIC_RELAXED, __HIP_MEMORY_SCOPE_AGENT);
        float sv = cv * hv;
        float2 x2 = *(const float2*)(x + r * 1024 + d0);
        float accx = D2.x * x2.x, accy = D2.y * x2.y;
#pragma unroll
        for (int s = 0; s < 16; s++) {
          float svs = __shfl(sv, s);
          accx = fmaf(wa[s], svs, accx);
          accy = fmaf(wb[s], svs, accy);
        }
        float2 o2; o2.x = accx; o2.y = accy;
        *(float2*)(y + r * 1024 + d0) = o2;
      }
    }
    return;
  }

  // ============================== SCAN ROLE ==============================
  const int b   = blockIdx.x;
  const float* pm = mask + (size_t)b * 4096;
  const size_t uvbase = (size_t)b * 4096 * 32;   // floats
  const size_t hsbase = (size_t)b * 4096 * 16;   // floats

  float h = 0.f, r = 0.f;
  if (tid < 16) {
    h = h0[b * 16 + tid];
    r = 0.5f - 0.5f * h;        // invariant r = (1-h)/2
  }

  // ---- priming: load chunk 0 (UV + mask)
  if (tid >= 64) {
    int pt = tid - 64;                          // 0..447
    const uint4* src = (const uint4*)(UV + uvbase);
    for (int i = pt; i < TC * 8; i += 448) ((uint4*)uvL[0])[i] = src[i];
    if (tid < 128) {
      int l = tid - 64;
      mskL[0][l]      = pm[l];
      mskL[0][l + 64] = pm[l + 64];
    }
  }
  __syncthreads();

  for (int c = 0; c < NCH; ++c) {
    // publish chunks 0..c-2: their agent-scope write-through stores were
    // drained by iteration c-1's pre-barrier vmcnt(0), so a bare relaxed
    // store suffices (no wbl2 -- see header). __syncthreads is also a
    // compiler fence, so this store cannot be hoisted above it.
    if (c >= 2 && tid == 511) {
      __hip_atomic_store(&flags[b], c - 1, __ATOMIC_RELAXED,
                         __HIP_MEMORY_SCOPE_AGENT);
    }
    const int p = c & 1;
    if (tid < 64) {
      // ---------------- consumer wave
      const int lane = tid;
      float mv0 = mskL[p][2 * lane], mv1 = mskL[p][2 * lane + 1];
      bool on = (mv0 == 1.0f) && (mv1 == 1.0f);
      bool allones = (__ballot(on) == 0xFFFFFFFFFFFFFFFFull);
      if (lane < 16) {
        const float* uvb = uvL[p];
        float* hhb = hhL[p];
        float2 Pa[16], Pb[16];
        load16(Pa, uvb, 0, lane);
        if (allones) {
#pragma unroll
          for (int j = 0; j < 8; j += 2) {
            load16(Pb, uvb, j + 1, lane);
            fast16(Pa, r, h, hhb, j, lane);
            if (j + 2 < 8) load16(Pa, uvb, j + 2, lane);
            fast16(Pb, r, h, hhb, j + 1, lane);
          }
          // h already = 1 - 2r
        } else {
#pragma unroll
          for (int j = 0; j < 8; j += 2) {
            load16(Pb, uvb, j + 1, lane);
            slow16(Pa, h, mskL[p], hhb, j, lane);
            if (j + 2 < 8) load16(Pa, uvb, j + 2, lane);
            slow16(Pb, h, mskL[p], hhb, j + 1, lane);
          }
          r = 0.5f - 0.5f * h;
        }
      }
    } else {
      // ---------------- producer waves 1..7
      int pt = tid - 64;                        // 0..447
      if (c + 1 < NCH) {
        const uint4* src =
            (const uint4*)(UV + uvbase + (size_t)(c + 1) * TC * 32);
        uint4* dst = (uint4*)uvL[(c + 1) & 1];
        for (int i = pt; i < TC * 8; i += 448) dst[i] = src[i];
        if (tid < 128) {
          int l = tid - 64;
          mskL[(c + 1) & 1][l]      = pm[(c + 1) * TC + l];
          mskL[(c + 1) & 1][l + 64] = pm[(c + 1) * TC + l + 64];
        }
      }
      if (c > 0) {
        // flush chunk c-1 h-history: agent-scope write-through 8B stores
        // (reach the coherence point; drained by this iteration's barrier)
        const unsigned long long* s2 = (const unsigned long long*)hhL[(c - 1) & 1];
        unsigned long long* d2 =
            (unsigned long long*)(hs + hsbase + (size_t)(c - 1) * TC * 16);
        for (int i = pt; i < TC * 8; i += 448)
          __hip_atomic_store(&d2[i], s2[i], __ATOMIC_RELAXED,
                             __HIP_MEMORY_SCOPE_AGENT);
      }
    }
    __syncthreads();
  }

  // ---- epilogue: store last chunk's h-history (parity (NCH-1)&1 = 1)
  {
    const unsigned long long* s2 = (const unsigned long long*)hhL[(NCH - 1) & 1];
    unsigned long long* d2 =
        (unsigned long long*)(hs + hsbase + (size_t)(NCH - 1) * TC * 16);
    for (int i = tid; i < TC * 8; i += 512)
      __hip_atomic_store(&d2[i], s2[i], __ATOMIC_RELAXED,
                         __HIP_MEMORY_SCOPE_AGENT);
  }
  __syncthreads();                              // drains vmcnt: epi + ch30 flush
  if (tid == 511) {
    __hip_atomic_store(&flags[b], NCH, __ATOMIC_RELAXED,
                       __HIP_MEMORY_SCOPE_AGENT);
  }
  if (tid < 16) hfin[b * 16 + tid] = h;
}

// ---------------------------------------------------------------- launcher
extern "C" void kernel_launch(void* const* d_in, const int* in_sizes, int n_in,
                              void* d_out, int out_size, void* d_ws, size_t ws_size,
                              hipStream_t stream) {
  const float* x       = (const float*)d_in[0];
  const float* h0      = (const float*)d_in[1];
  const float* mask    = (const float*)d_in[2];
  const float* A_diag  = (const float*)d_in[3];
  const float* W_delta = (const float*)d_in[4];
  const float* W_B     = (const float*)d_in[5];
  const float* W_C     = (const float*)d_in[6];
  const float* W_out   = (const float*)d_in[7];
  const float* Dd      = (const float*)d_in[8];
  const float* W_gate  = (const float*)d_in[9];
  const float* b_gate  = (const float*)d_in[10];
  const float* ln_w    = (const float*)d_in[11];
  const float* ln_b    = (const float*)d_in[12];

  char* ws = (char*)d_ws;
  unsigned short* Xb   = (unsigned short*)(ws);               // 64 MB
  unsigned short* Gb   = (unsigned short*)(ws + 67108864);    // 64 MB (G, then xg in-place)
  unsigned short* Wgb  = (unsigned short*)(ws + 134217728);   // 2 MB
  unsigned short* Wcat = (unsigned short*)(ws + 136314880);   // 96 KB used of 128 KB slot
  int* flags = (int*)(ws + 136413184);                        // 32 B, inside Wcat pad gap
  float* UVb = (float*)(ws + 136445952);                      // 4 MB interleaved {u,v}
  float* Ctb = (float*)(ws + 140640256);                      // 2 MB
  float* hsb = (float*)(ws + 142737408);                      // 2 MB  (end 144834560, same as verified kernel)

  float* y    = (float*)d_out;
  float* hfin = y + 33554432;

  hipLaunchKernelGGL(k_convert, dim3(33840), dim3(256), 0, stream,
                     x, W_gate, W_delta, W_B, W_C, Xb, Wgb, Wcat);
  hipLaunchKernelGGL(k_gemm_gate, dim3(256, 8), dim3(256), 0, stream, Xb, Wgb, Gb);
  hipLaunchKernelGGL(k_lngate, dim3(32768), dim3(256), 0, stream,
                     Gb, x, b_gate, ln_w, ln_b, Gb);
  hipLaunchKernelGGL(k_proj, dim3(512), dim3(256), 0, stream,
                     Gb, Wcat, A_diag, UVb, Ctb, flags);
  hipLaunchKernelGGL(k_scan_out, dim3(8 + NOUT), dim3(512), 0, stream,
                     UVb, mask, h0, hsb, hfin, Ctb, x, W_out, Dd, y, flags);
}

// Round 4
// 500.618 us; speedup vs baseline: 1.1014x; 1.0124x over previous
//
#include <hip/hip_runtime.h>
#include <hip/hip_bf16.h>
#include <cstdint>

// SimplifiedMambaSSM on MI355X (gfx950)
// B=8, T=4096, D_MODEL=1024, D_STATE=16. Rows M = B*T = 32768.
//
// Pipeline:
//  K1 convert : x, W_gate, [W_delta;W_B;W_C] -> bf16 workspace copies
//  K2 gemm    : G = Xb @ Wgb^T   (32768x1024x1024 bf16 MFMA, 128x128 tiles,
//               XCD-swizzled grid)
//  K3 lngate  : xg = sigmoid(LN(G + b_gate)) * x   (in-place over G, bf16)
//  K4 proj    : [delta|B|C] = xg @ Wcat^T (skinny MFMA); epilogue folds
//               softplus/exp(A_diag)/2*log2e and the r-domain substitution
//               {u = A2+B2, v = -2*A2}; zeroes the chunk-ready flags.
//  K5 scan+out: FUSED producer-consumer kernel.
//               Blocks 0..7: wave-specialized scan (one per batch).
//                 Consumer wave runs at s_setprio(3): its 4-op dependent
//                 chain (fma->exp2->add->rcp, 62.9 cyc/step standalone) is
//                 latency-bound; priority makes it win SIMD issue
//                 arbitration against co-resident output waves (R3 lesson:
//                 fused scan ran 145us vs 107us standalone with bytes at
//                 only 23% of peak -> contention/tail, not HBM).
//                 hs flushed with agent-scope write-through stores; flag
//                 publish is a bare relaxed agent store (barrier already
//                 drained vmcnt).
//               Blocks 8..519: output GEMM y = (C.*h)@W_out^T + D.*x,
//                 chunk-major, TWO rows per iteration (block o handles
//                 (b,j) and (b+4,j), b=o>>7, j=o&127) to double in-flight
//                 HBM loads per wave; spin on flags (bounded ~0.2s).
//                 One-way dependency + scan blocks dispatch first =>
//                 deadlock-free; bounded spin converts any visibility bug
//                 into absmax failure, never a hang.
//
#define M_TOK   32768
#define LNEPS   1e-5f
#define TWO_LOG2E 2.8853900817779268f   // 2/ln(2)

typedef float  f32x4 __attribute__((ext_vector_type(4)));
typedef short  s16x8 __attribute__((ext_vector_type(8)));

__device__ __forceinline__ unsigned short f2b(float v) {
  return __builtin_bit_cast(unsigned short, __float2bfloat16(v));
}
__device__ __forceinline__ float b2f(unsigned short u) {
  return __bfloat162float(__builtin_bit_cast(__hip_bfloat16, u));
}

// async global->LDS, 16B per lane. LDS dest is wave-uniform base + lane*16.
__device__ __forceinline__ void async_cp16(const void* g, void* l) {
  using gp = const __attribute__((address_space(1))) char*;
  using lp = __attribute__((address_space(3))) char*;
  __builtin_amdgcn_global_load_lds((gp)(uint64_t)g,
                                   (lp)(uint32_t)(uint64_t)l, 16, 0, 0);
}

// ---------------------------------------------------------------- K1 convert
__global__ __launch_bounds__(256) void k_convert(
    const float* __restrict__ x, const float* __restrict__ wg,
    const float* __restrict__ wd, const float* __restrict__ wb,
    const float* __restrict__ wc,
    unsigned short* __restrict__ Xb, unsigned short* __restrict__ Wgb,
    unsigned short* __restrict__ Wcat) {
  int i = blockIdx.x * 256 + threadIdx.x;   // one float4 per thread
  const float* src;
  unsigned short* dst;
  if (i < 8388608) {                  // x: 33554432 floats
    src = x + (size_t)i * 4; dst = Xb + (size_t)i * 4;
  } else if (i < 8650752) {           // W_gate: 1048576 floats
    int j = i - 8388608;
    src = wg + (size_t)j * 4; dst = Wgb + (size_t)j * 4;
  } else {                            // Wcat = [W_delta; W_B; W_C], 49152 floats
    int j = i - 8650752;
    int e = j * 4;
    if (e < 16384)       src = wd + e;
    else if (e < 32768)  src = wb + (e - 16384);
    else                 src = wc + (e - 32768);
    dst = Wcat + e;
  }
  float4 v = *(const float4*)src;
  ushort4 o;
  o.x = f2b(v.x); o.y = f2b(v.y); o.z = f2b(v.z); o.w = f2b(v.w);
  *(ushort4*)dst = o;
}

// ------------------------------------------------------------- K2 gate GEMM
// G[m][n] = sum_k Xb[m][k] * Wgb[n][k]   (NT, both K-contiguous)
// 128x128 block tile, 4 waves in 2x2, each wave 64x64 = 4x4 MFMA 16x16x32.
__global__ __launch_bounds__(256, 2) void k_gemm_gate(
    const unsigned short* __restrict__ A,   // [32768][1024] bf16
    const unsigned short* __restrict__ Bm,  // [1024][1024] bf16 (W_gate rows)
    unsigned short* __restrict__ C) {       // [32768][1024] bf16
  __shared__ unsigned short As[128 * 32];   // 8 KB
  __shared__ unsigned short Bs[128 * 32];   // 8 KB
  const int tid  = threadIdx.x;
  const int wave = tid >> 6, lane = tid & 63;
  const int wr = wave >> 1, wc = wave & 1;
  const int lrow = lane & 15, lq = lane >> 4;
  // XCD-aware swizzle: lin 0..2047 round-robins XCDs; give each XCD a
  // contiguous chunk of 32 M-panels x all 8 N-tiles so A-panels and the
  // whole 2MB B stay L2-resident per XCD. 2048 % 8 == 0 -> bijective.
  const int lin  = blockIdx.y * gridDim.x + blockIdx.x;     // 0..2047
  const int unit = (lin & 7) * 256 + (lin >> 3);
  const int m0 = (unit >> 3) * 128;
  const int n0 = (unit & 7) * 128;
  const int crow  = tid >> 2;               // staging chunk row (rep 0)
  const int ccol  = (tid & 3) * 8;          // staging chunk col (elems)

  f32x4 acc[4][4];
#pragma unroll
  for (int i = 0; i < 4; i++)
#pragma unroll
    for (int j = 0; j < 4; j++) acc[i][j] = (f32x4){0.f, 0.f, 0.f, 0.f};

  for (int k0 = 0; k0 < 1024; k0 += 32) {
    async_cp16(A + (size_t)(m0 + crow) * 1024 + k0 + ccol,
               (void*)(As + (wave * 64) * 8));
    async_cp16(A + (size_t)(m0 + crow + 64) * 1024 + k0 + ccol,
               (void*)(As + (256 + wave * 64) * 8));
    async_cp16(Bm + (size_t)(n0 + crow) * 1024 + k0 + ccol,
               (void*)(Bs + (wave * 64) * 8));
    async_cp16(Bm + (size_t)(n0 + crow + 64) * 1024 + k0 + ccol,
               (void*)(Bs + (256 + wave * 64) * 8));
    __syncthreads();   // drains vmcnt (global_load_lds) before LDS reads

    s16x8 af[4], bfr[4];
#pragma unroll
    for (int i = 0; i < 4; i++)
      af[i] = *(const s16x8*)(As + (wr * 64 + i * 16 + lrow) * 32 + lq * 8);
#pragma unroll
    for (int j = 0; j < 4; j++)
      bfr[j] = *(const s16x8*)(Bs + (wc * 64 + j * 16 + lrow) * 32 + lq * 8);
#pragma unroll
    for (int i = 0; i < 4; i++)
#pragma unroll
      for (int j = 0; j < 4; j++)
        acc[i][j] = __builtin_amdgcn_mfma_f32_16x16x32_bf16(
            af[i], bfr[j], acc[i][j], 0, 0, 0);
    __syncthreads();
  }

  // C/D layout: col = lane&15, row = (lane>>4)*4 + reg
#pragma unroll
  for (int i = 0; i < 4; i++)
#pragma unroll
    for (int j = 0; j < 4; j++)
#pragma unroll
      for (int r = 0; r < 4; r++) {
        int row = m0 + wr * 64 + i * 16 + lq * 4 + r;
        int col = n0 + wc * 64 + j * 16 + lrow;
        C[(size_t)row * 1024 + col] = f2b(acc[i][j][r]);
      }
}

// -------------------------------------------------------------- K3 LN+gate
__global__ __launch_bounds__(256) void k_lngate(
    const unsigned short* Gin, const float* __restrict__ x,
    const float* __restrict__ bg, const float* __restrict__ lnw,
    const float* __restrict__ lnb, unsigned short* XG) {
  __shared__ float red[8];
  const int t = threadIdx.x;
  const size_t r = blockIdx.x;
  const int e = t * 4;

  ushort4 g4 = *(const ushort4*)(Gin + r * 1024 + e);
  float4 bg4 = *(const float4*)(bg + e);
  float v0 = b2f(g4.x) + bg4.x;
  float v1 = b2f(g4.y) + bg4.y;
  float v2 = b2f(g4.z) + bg4.z;
  float v3 = b2f(g4.w) + bg4.w;

  float s  = v0 + v1 + v2 + v3;
  float ss = v0 * v0 + v1 * v1 + v2 * v2 + v3 * v3;
#pragma unroll
  for (int off = 32; off >= 1; off >>= 1) {
    s  += __shfl_xor(s, off, 64);
    ss += __shfl_xor(ss, off, 64);
  }
  if ((t & 63) == 0) { red[t >> 6] = s; red[4 + (t >> 6)] = ss; }
  __syncthreads();
  float tot = red[0] + red[1] + red[2] + red[3];
  float tss = red[4] + red[5] + red[6] + red[7];
  float mu  = tot * (1.0f / 1024.0f);
  float var = tss * (1.0f / 1024.0f) - mu * mu;
  float rs  = rsqrtf(var + LNEPS);

  float4 xv = *(const float4*)(x + r * 1024 + e);
  float4 w4 = *(const float4*)(lnw + e);
  float4 b4 = *(const float4*)(lnb + e);
  float u0 = (v0 - mu) * rs * w4.x + b4.x;
  float u1 = (v1 - mu) * rs * w4.y + b4.y;
  float u2 = (v2 - mu) * rs * w4.z + b4.z;
  float u3 = (v3 - mu) * rs * w4.w + b4.w;
  float g0 = 1.0f / (1.0f + __expf(-u0));
  float g1 = 1.0f / (1.0f + __expf(-u1));
  float g2 = 1.0f / (1.0f + __expf(-u2));
  float g3 = 1.0f / (1.0f + __expf(-u3));
  ushort4 o;
  o.x = f2b(g0 * xv.x); o.y = f2b(g1 * xv.y);
  o.z = f2b(g2 * xv.z); o.w = f2b(g3 * xv.w);
  *(ushort4*)(XG + r * 1024 + e) = o;
}

// ------------------------------------------------------------ K4 projection
// Epilogue writes UV[row*32 + s*2] = {u = A2+B2, v = -2*A2} where
// A2 = exp(softplus(delta)*A_diag)*2log2e, B2 = B*2log2e. Ct written flat.
// Also zeroes the 8 chunk-ready flags consumed by K5.
__global__ __launch_bounds__(256) void k_proj(
    const unsigned short* __restrict__ XG, const unsigned short* __restrict__ Wcat,
    const float* __restrict__ A_diag,
    float* __restrict__ UV, float* __restrict__ Ct, int* __restrict__ flags) {
  __shared__ unsigned short As[64 * 32];   // 4 KB
  __shared__ unsigned short Bs[48 * 32];   // 3 KB
  const int tid  = threadIdx.x;
  const int wave = tid >> 6, lane = tid & 63;
  const int lrow = lane & 15, lq = lane >> 4;
  const int r0 = blockIdx.x * 64;
  const int crow = tid >> 2, ccol = (tid & 3) * 8;

  if (blockIdx.x == 0 && tid < 8)
    __hip_atomic_store(&flags[tid], 0, __ATOMIC_RELAXED,
                       __HIP_MEMORY_SCOPE_AGENT);   // write-through zeroing

  f32x4 acc[3];
#pragma unroll
  for (int j = 0; j < 3; j++) acc[j] = (f32x4){0.f, 0.f, 0.f, 0.f};

  for (int k0 = 0; k0 < 1024; k0 += 32) {
    uint4 av = *(const uint4*)(XG + (size_t)(r0 + crow) * 1024 + k0 + ccol);
    uint4 bv;
    if (tid < 192) bv = *(const uint4*)(Wcat + (size_t)crow * 1024 + k0 + ccol);
    __syncthreads();                       // prev iter done reading LDS
    *(uint4*)(As + crow * 32 + ccol) = av;
    if (tid < 192) *(uint4*)(Bs + crow * 32 + ccol) = bv;
    __syncthreads();
    s16x8 af = *(const s16x8*)(As + (wave * 16 + lrow) * 32 + lq * 8);
#pragma unroll
    for (int j = 0; j < 3; j++) {
      s16x8 bf8 = *(const s16x8*)(Bs + (j * 16 + lrow) * 32 + lq * 8);
      acc[j] = __builtin_amdgcn_mfma_f32_16x16x32_bf16(af, bf8, acc[j], 0, 0, 0);
    }
  }

  float ad = A_diag[lrow];
#pragma unroll
  for (int r = 0; r < 4; r++) {
    int row = r0 + wave * 16 + lq * 4 + r;
    float z  = acc[0][r];
    float sp = fmaxf(z, 0.0f) + log1pf(__expf(-fabsf(z)));  // softplus
    float A2 = __expf(sp * ad) * TWO_LOG2E;                  // A_bar scaled
    float B2 = acc[1][r] * TWO_LOG2E;
    float2 o;
    o.x = A2 + B2;          // u
    o.y = -2.0f * A2;       // v
    *(float2*)(UV + (size_t)row * 32 + lrow * 2) = o;
    Ct[(size_t)row * 16 + lrow] = acc[2][r];
  }
}

// --------------------------------------------------------- K5 scan + output
#define TC 128                // steps per chunk
#define NCH (4096 / TC)       // 32 chunks
#define NOUT 512              // output blocks; 1024 rows/chunk = 2 per block

__device__ __forceinline__ void load16(float2 (&P)[16], const float* uvb,
                                       int j, int lane) {
#pragma unroll
  for (int i = 0; i < 16; ++i)
    P[i] = *(const float2*)(uvb + ((j * 16 + i) * 16 + lane) * 2);
}
__device__ __forceinline__ void fast16(float2 (&P)[16], float& r, float& h,
                                       float* hhb, int j, int lane) {
#pragma unroll
  for (int i = 0; i < 16; ++i) {
    float w = fmaf(P[i].y, r, P[i].x);
    float e = __builtin_amdgcn_exp2f(w);
    r = __builtin_amdgcn_rcpf(e + 1.0f);
    h = fmaf(-2.0f, r, 1.0f);
    hhb[(j * 16 + i) * 16 + lane] = h;
  }
}
__device__ __forceinline__ void slow16(float2 (&P)[16], float& h,
                                       const float* mb, float* hhb,
                                       int j, int lane) {
#pragma unroll
  for (int i = 0; i < 16; ++i) {
    float v  = P[i].y, u = P[i].x;
    float A2 = -0.5f * v;
    float B2 = fmaf(0.5f, v, u);
    float w  = fmaf(A2, h, B2);
    float e  = __builtin_amdgcn_exp2f(w);
    float rr = __builtin_amdgcn_rcpf(e + 1.0f);
    float th = fmaf(-2.0f, rr, 1.0f);
    float m  = mb[j * 16 + i];
    h = fmaf(m, th - h, h);
    hhb[(j * 16 + i) * 16 + lane] = h;
  }
}

__global__ __launch_bounds__(512, 6) void k_scan_out(
    const float* __restrict__ UV, const float* __restrict__ mask,
    const float* __restrict__ h0, float* __restrict__ hs,
    float* __restrict__ hfin,
    const float* __restrict__ Ct, const float* __restrict__ x,
    const float* __restrict__ Wout, const float* __restrict__ Dd,
    float* __restrict__ y, int* __restrict__ flags) {
  __shared__ float uvL[2][TC * 32];    // 2 x 16 KB
  __shared__ float hhL[2][TC * 16];    // 2 x 8 KB
  __shared__ float mskL[2][TC];        // 2 x 512 B

  const int tid = threadIdx.x;

  if (blockIdx.x >= 8) {
    // ============================ OUTPUT ROLE ============================
    // y[r][d] = D[d]*x[r][d] + sum_s W_out[d][s] * (Ct[r][s]*hs[r][s])
    // Block o handles rows (b,j) and (b+4,j), b=o>>7, j=o&127, per chunk:
    // two independent x-loads in flight per wave-iteration.
    const int o    = blockIdx.x - 8;          // 0..511
    const int wv   = tid >> 6;
    const int lane = tid & 63;
    const int d0   = wv * 128 + lane * 2;
    const int b0   = o >> 7;                  // 0..3
    const int b1   = b0 + 4;                  // 4..7
    const int j0   = o & 127;

    float wa[16], wb[16];
#pragma unroll
    for (int q = 0; q < 4; q++) {
      *(float4*)&wa[q * 4] = *(const float4*)(Wout + (size_t)d0 * 16 + q * 4);
      *(float4*)&wb[q * 4] = *(const float4*)(Wout + (size_t)(d0 + 1) * 16 + q * 4);
    }
    float2 D2 = *(const float2*)(Dd + d0);

    for (int c = 0; c < NCH; ++c) {
      size_t r0 = (size_t)b0 * 4096 + (size_t)c * TC + j0;
      size_t r1 = (size_t)b1 * 4096 + (size_t)c * TC + j0;
      // wait until chunk c of both batches is published. BOUNDED: ~0.2s
      // cap converts any visibility pathology into a wrong answer, never
      // a hung container. Never hit in the expected path.
      int spins = 0;
      for (;;) {
        int f = 0;
        if (lane == 0) {
          int fa = __hip_atomic_load(&flags[b0], __ATOMIC_RELAXED,
                                     __HIP_MEMORY_SCOPE_AGENT);
          int fb = __hip_atomic_load(&flags[b1], __ATOMIC_RELAXED,
                                     __HIP_MEMORY_SCOPE_AGENT);
          f = (fa < fb) ? fa : fb;
        }
        f = __shfl(f, 0);
        if (f > c || spins > (1 << 18)) break;
        ++spins;
        __builtin_amdgcn_s_sleep(32);
      }
      // issue all loads up-front (2 rows -> ~1KB HBM in flight per wave)
      float cv0 = Ct[r0 * 16 + (lane & 15)];
      float cv1 = Ct[r1 * 16 + (lane & 15)];
      // agent-scope loads: bypass stale local L2; writer stored these
      // write-through and drained vmcnt before publishing the flag.
      float hv0 = __hip_atomic_load(&hs[r0 * 16 + (lane & 15)],
                                    __ATOMIC_RELAXED, __HIP_MEMORY_SCOPE_AGENT);
      float hv1 = __hip_atomic_load(&hs[r1 * 16 + (lane & 15)],
                                    __ATOMIC_RELAXED, __HIP_MEMORY_SCOPE_AGENT);
      float2 x20 = *(const float2*)(x + r0 * 1024 + d0);
      float2 x21 = *(const float2*)(x + r1 * 1024 + d0);
      float sv0 = cv0 * hv0;
      float sv1 = cv1 * hv1;
      float a0x = D2.x * x20.x, a0y = D2.y * x20.y;
      float a1x = D2.x * x21.x, a1y = D2.y * x21.y;
#pragma unroll
      for (int s = 0; s < 16; s++) {
        float s0 = __shfl(sv0, s);
        float s1 = __shfl(sv1, s);
        a0x = fmaf(wa[s], s0, a0x);
        a0y = fmaf(wb[s], s0, a0y);
        a1x = fmaf(wa[s], s1, a1x);
        a1y = fmaf(wb[s], s1, a1y);
      }
      float2 o0; o0.x = a0x; o0.y = a0y;
      float2 o1; o1.x = a1x; o1.y = a1y;
      *(float2*)(y + r0 * 1024 + d0) = o0;
      *(float2*)(y + r1 * 1024 + d0) = o1;
    }
    return;
  }

  // ============================== SCAN ROLE ==============================
  const int b   = blockIdx.x;
  const float* pm = mask + (size_t)b * 4096;
  const size_t uvbase = (size_t)b * 4096 * 32;   // floats
  const size_t hsbase = (size_t)b * 4096 * 16;   // floats

  // Critical wave: top scheduler priority so the latency-bound recurrence
  // chain never loses SIMD issue arbitration to co-resident output waves.
  if (tid < 64) __builtin_amdgcn_s_setprio(3);

  float h = 0.f, r = 0.f;
  if (tid < 16) {
    h = h0[b * 16 + tid];
    r = 0.5f - 0.5f * h;        // invariant r = (1-h)/2
  }

  // ---- priming: load chunk 0 (UV + mask)
  if (tid >= 64) {
    int pt = tid - 64;                          // 0..447
    const uint4* src = (const uint4*)(UV + uvbase);
    for (int i = pt; i < TC * 8; i += 448) ((uint4*)uvL[0])[i] = src[i];
    if (tid < 128) {
      int l = tid - 64;
      mskL[0][l]      = pm[l];
      mskL[0][l + 64] = pm[l + 64];
    }
  }
  __syncthreads();

  for (int c = 0; c < NCH; ++c) {
    // publish chunks 0..c-2: their agent-scope write-through stores were
    // drained by iteration c-1's pre-barrier vmcnt(0), so a bare relaxed
    // store suffices. __syncthreads is also a compiler fence.
    if (c >= 2 && tid == 511) {
      __hip_atomic_store(&flags[b], c - 1, __ATOMIC_RELAXED,
                         __HIP_MEMORY_SCOPE_AGENT);
    }
    const int p = c & 1;
    if (tid < 64) {
      // ---------------- consumer wave
      const int lane = tid;
      float mv0 = mskL[p][2 * lane], mv1 = mskL[p][2 * lane + 1];
      bool on = (mv0 == 1.0f) && (mv1 == 1.0f);
      bool allones = (__ballot(on) == 0xFFFFFFFFFFFFFFFFull);
      if (lane < 16) {
        const float* uvb = uvL[p];
        float* hhb = hhL[p];
        float2 Pa[16], Pb[16];
        load16(Pa, uvb, 0, lane);
        if (allones) {
#pragma unroll
          for (int j = 0; j < 8; j += 2) {
            load16(Pb, uvb, j + 1, lane);
            fast16(Pa, r, h, hhb, j, lane);
            if (j + 2 < 8) load16(Pa, uvb, j + 2, lane);
            fast16(Pb, r, h, hhb, j + 1, lane);
          }
          // h already = 1 - 2r
        } else {
#pragma unroll
          for (int j = 0; j < 8; j += 2) {
            load16(Pb, uvb, j + 1, lane);
            slow16(Pa, h, mskL[p], hhb, j, lane);
            if (j + 2 < 8) load16(Pa, uvb, j + 2, lane);
            slow16(Pb, h, mskL[p], hhb, j + 1, lane);
          }
          r = 0.5f - 0.5f * h;
        }
      }
    } else {
      // ---------------- producer waves 1..7
      int pt = tid - 64;                        // 0..447
      if (c + 1 < NCH) {
        const uint4* src =
            (const uint4*)(UV + uvbase + (size_t)(c + 1) * TC * 32);
        uint4* dst = (uint4*)uvL[(c + 1) & 1];
        for (int i = pt; i < TC * 8; i += 448) dst[i] = src[i];
        if (tid < 128) {
          int l = tid - 64;
          mskL[(c + 1) & 1][l]      = pm[(c + 1) * TC + l];
          mskL[(c + 1) & 1][l + 64] = pm[(c + 1) * TC + l + 64];
        }
      }
      if (c > 0) {
        // flush chunk c-1 h-history: agent-scope write-through 8B stores
        // (reach the coherence point; drained by this iteration's barrier)
        const unsigned long long* s2 = (const unsigned long long*)hhL[(c - 1) & 1];
        unsigned long long* d2 =
            (unsigned long long*)(hs + hsbase + (size_t)(c - 1) * TC * 16);
        for (int i = pt; i < TC * 8; i += 448)
          __hip_atomic_store(&d2[i], s2[i], __ATOMIC_RELAXED,
                             __HIP_MEMORY_SCOPE_AGENT);
      }
    }
    __syncthreads();
  }

  // ---- epilogue: store last chunk's h-history (parity (NCH-1)&1 = 1)
  {
    const unsigned long long* s2 = (const unsigned long long*)hhL[(NCH - 1) & 1];
    unsigned long long* d2 =
        (unsigned long long*)(hs + hsbase + (size_t)(NCH - 1) * TC * 16);
    for (int i = tid; i < TC * 8; i += 512)
      __hip_atomic_store(&d2[i], s2[i], __ATOMIC_RELAXED,
                         __HIP_MEMORY_SCOPE_AGENT);
  }
  __syncthreads();                              // drains vmcnt: epi + ch30 flush
  if (tid == 511) {
    __hip_atomic_store(&flags[b], NCH, __ATOMIC_RELAXED,
                       __HIP_MEMORY_SCOPE_AGENT);
  }
  if (tid < 16) hfin[b * 16 + tid] = h;
}

// ---------------------------------------------------------------- launcher
extern "C" void kernel_launch(void* const* d_in, const int* in_sizes, int n_in,
                              void* d_out, int out_size, void* d_ws, size_t ws_size,
                              hipStream_t stream) {
  const float* x       = (const float*)d_in[0];
  const float* h0      = (const float*)d_in[1];
  const float* mask    = (const float*)d_in[2];
  const float* A_diag  = (const float*)d_in[3];
  const float* W_delta = (const float*)d_in[4];
  const float* W_B     = (const float*)d_in[5];
  const float* W_C     = (const float*)d_in[6];
  const float* W_out   = (const float*)d_in[7];
  const float* Dd      = (const float*)d_in[8];
  const float* W_gate  = (const float*)d_in[9];
  const float* b_gate  = (const float*)d_in[10];
  const float* ln_w    = (const float*)d_in[11];
  const float* ln_b    = (const float*)d_in[12];

  char* ws = (char*)d_ws;
  unsigned short* Xb   = (unsigned short*)(ws);               // 64 MB
  unsigned short* Gb   = (unsigned short*)(ws + 67108864);    // 64 MB (G, then xg in-place)
  unsigned short* Wgb  = (unsigned short*)(ws + 134217728);   // 2 MB
  unsigned short* Wcat = (unsigned short*)(ws + 136314880);   // 96 KB used of 128 KB slot
  int* flags = (int*)(ws + 136413184);                        // 32 B, inside Wcat pad gap
  float* UVb = (float*)(ws + 136445952);                      // 4 MB interleaved {u,v}
  float* Ctb = (float*)(ws + 140640256);                      // 2 MB
  float* hsb = (float*)(ws + 142737408);                      // 2 MB  (end 144834560, same as verified kernel)

  float* y    = (float*)d_out;
  float* hfin = y + 33554432;

  hipLaunchKernelGGL(k_convert, dim3(33840), dim3(256), 0, stream,
                     x, W_gate, W_delta, W_B, W_C, Xb, Wgb, Wcat);
  hipLaunchKernelGGL(k_gemm_gate, dim3(256, 8), dim3(256), 0, stream, Xb, Wgb, Gb);
  hipLaunchKernelGGL(k_lngate, dim3(32768), dim3(256), 0, stream,
                     Gb, x, b_gate, ln_w, ln_b, Gb);
  hipLaunchKernelGGL(k_proj, dim3(512), dim3(256), 0, stream,
                     Gb, Wcat, A_diag, UVb, Ctb, flags);
  hipLaunchKernelGGL(k_scan_out, dim3(8 + NOUT), dim3(512), 0, stream,
                     UVb, mask, h0, hsb, hfin, Ctb, x, W_out, Dd, y, flags);
}